// Round 16
// baseline (462.318 us; speedup 1.0000x reference)
//
#include <hip/hip_runtime.h>
#include <cfloat>

// Problem dims (fixed): z_e [8,2048,768] f32, embedding [8192,768] f32.
#define NROWS 16384
#define DIM   768
#define KC    8192
#define MARGIN 2.5e-4f
#define NBLK_EMIT (NROWS / 4)   // 4096 blocks, 4 rows each

// gemm2 tiling (r7/r10/r13-proven)
#define BM 256
#define BN 256
#define BK 32
#define NKT (DIM / BK)          // 24 K-tiles (= 8 ring periods of 3)
#define NCB (KC / BN)           // 32 code-blocks per row

#define NBLK_ZCVT (NROWS / 4)           // 4096 blocks: z cvt + x2
#define NBLK_ECVT (KC * DIM / 8 / 256)  // 3072 blocks: emb cvt

typedef unsigned short ushort_t;
typedef __attribute__((ext_vector_type(8))) short short8v;  // 8 bf16 (4 VGPR)
typedef __attribute__((ext_vector_type(4))) float f32x4;

__device__ __forceinline__ ushort_t f2bf(float f) {
  unsigned u = __float_as_uint(f);
  return (ushort_t)((u + 0x7FFFu + ((u >> 16) & 1u)) >> 16);
}

__device__ __forceinline__ void gload_lds16(const void* g, void* l) {
  using GP = const __attribute__((address_space(1))) void*;
  using LP = __attribute__((address_space(3))) void*;
  GP gp = (GP)(unsigned long long)(uintptr_t)g;
  LP lp = (LP)(unsigned)(uintptr_t)l;
  __builtin_amdgcn_global_load_lds(gp, lp, 16, 0, 0);
}

// ---------------------------------------------------------------------------
// K0: merged conversion kernel (one launch) — r15-proven.
// ---------------------------------------------------------------------------
__global__ __launch_bounds__(256)
void cvt_all_kernel(const float* __restrict__ z, ushort_t* __restrict__ zh,
                    float* __restrict__ x2, const float* __restrict__ emb,
                    ushort_t* __restrict__ eh) {
#pragma clang fp contract(off)
  if (blockIdx.x < NBLK_ZCVT) {
    const int w    = threadIdx.x >> 6;
    const int lane = threadIdx.x & 63;
    const int n    = blockIdx.x * 4 + w;
    const float* zr = z + (size_t)n * DIM;

    {
      const float4* zg = (const float4*)zr;
      uint2* zo = (uint2*)(zh + (size_t)n * DIM);
      #pragma unroll
      for (int i = 0; i < 3; ++i) {
        const float4 f = zg[lane + 64 * i];
        uint2 o;
        o.x = (unsigned)f2bf(f.x) | ((unsigned)f2bf(f.y) << 16);
        o.y = (unsigned)f2bf(f.z) | ((unsigned)f2bf(f.w) << 16);
        zo[lane + 64 * i] = o;
      }
    }

    const int chunk = lane >> 3;
    const int j     = lane & 7;
    const float* p  = zr + chunk * 96 + j;
    float v0 = p[0];
    float r  = v0 * v0;
    #pragma unroll
    for (int k = 1; k < 12; ++k) {
      const float v  = p[8 * k];
      const float sq = v * v;
      r = r + sq;
    }
    r = r + __shfl_xor(r, 1);
    r = r + __shfl_xor(r, 2);
    r = r + __shfl_xor(r, 4);
    r = r + __shfl_xor(r, 8);
    r = r + __shfl_xor(r, 16);
    r = r + __shfl_xor(r, 32);
    if (lane == 0) x2[n] = r;
  } else {
    const int i = (blockIdx.x - NBLK_ZCVT) * 256 + threadIdx.x;
    const float4* s4 = (const float4*)emb;
    const float4 f0 = s4[2 * i], f1 = s4[2 * i + 1];
    uint4 o;
    o.x = (unsigned)f2bf(f0.x) | ((unsigned)f2bf(f0.y) << 16);
    o.y = (unsigned)f2bf(f0.z) | ((unsigned)f2bf(f0.w) << 16);
    o.z = (unsigned)f2bf(f1.x) | ((unsigned)f2bf(f1.y) << 16);
    o.w = (unsigned)f2bf(f1.z) | ((unsigned)f2bf(f1.w) << 16);
    ((uint4*)eh)[i] = o;
  }
}

// ---------------------------------------------------------------------------
// K2: gemm5 — r10 K-loop with the two manual intra-step lgkmcnt(0)+
// sched_barrier drains REMOVED (r15 post-mortem: they serialize the LDS-read
// phase against the MFMA phase; the compiler emits fine-grained lgkmcnt(N)
// per dependent MFMA on its own — m97 asm evidence). Ring safety unchanged:
// one lgkmcnt(0) BEFORE the end-of-step barrier (reads complete before the
// slot is overwritten; ~free since MFMAs already consumed them) + counted
// vmcnt(4) + s_barrier + fence. setprio dropped (T5 NULL for this structure,
// m190). __launch_bounds__(512,2): 256-reg budget (r11/r12-proven no-spill);
// LDS 112KB caps 1 block/CU regardless.
// Accumulation order per acc[m][n] unchanged (ascending kt) -> scores
// bitwise identical to r10/r13/r15.
// ---------------------------------------------------------------------------
__global__ __launch_bounds__(512, 2)
void gemm5(const ushort_t* __restrict__ zh, const ushort_t* __restrict__ eh,
           float4* __restrict__ subtop) {
  __shared__ __align__(16) ushort_t Ash[3][BM * BK];   // 3 x 16KB
  __shared__ __align__(16) ushort_t Bsh[3][BN * BK];   // 3 x 16KB
  __shared__ float4 ltop[BM][4];                       // 16KB

  const int t    = threadIdx.x;
  const int w    = t >> 6, lane = t & 63;
  const int wr   = w >> 2;          // 0..1 : 128-row half
  const int wcn  = w & 3;           // 0..3 : 64-col group
  const int row0 = blockIdx.y * BM;
  const int col0 = blockIdx.x * BN;

  const int srow  = w * 32 + (lane >> 2);
  const int sslot = lane & 3;
  const ushort_t* zsA[2];
  const ushort_t* esB[2];
  #pragma unroll
  for (int q = 0; q < 2; ++q) {
    const int r = srow + q * 16;
    const int j = sslot ^ ((r >> 1) & 3);
    zsA[q] = zh + (size_t)(row0 + r) * DIM + j * 8;
    esB[q] = eh + (size_t)(col0 + r) * DIM + j * 8;
  }

#define STAGE_A_S(ktv, SLOT) do {                                         \
    _Pragma("unroll")                                                     \
    for (int q = 0; q < 2; ++q)                                           \
      gload_lds16(zsA[q] + (ktv) * 32, &Ash[SLOT][w * 1024 + q * 512]);   \
  } while (0)
#define STAGE_B_S(ktv, SLOT) do {                                         \
    _Pragma("unroll")                                                     \
    for (int q = 0; q < 2; ++q)                                           \
      gload_lds16(esB[q] + (ktv) * 32, &Bsh[SLOT][w * 1024 + q * 512]);   \
  } while (0)

  f32x4 acc[8][4];
  #pragma unroll
  for (int m = 0; m < 8; ++m)
    #pragma unroll
    for (int n = 0; n < 4; ++n) acc[m][n] = (f32x4){0.f, 0.f, 0.f, 0.f};

  STAGE_A_S(0, 0); STAGE_B_S(0, 0);
  STAGE_A_S(1, 1); STAGE_B_S(1, 1);
  asm volatile("s_waitcnt vmcnt(4)" ::: "memory");
  __builtin_amdgcn_s_barrier();
  __builtin_amdgcn_sched_barrier(0);

#define TILE_STEP(ktv, RB, RS) do {                                           \
    short8v bfr[4], afr[8];                                                   \
    /* all 12 frag reads up front; compiler fine-waits per dependent MFMA */  \
    _Pragma("unroll")                                                         \
    for (int n = 0; n < 4; ++n) {                                             \
      const int c  = wcn * 64 + n * 16 + (lane & 15);                         \
      const int sl = (lane >> 4) ^ ((c >> 1) & 3);                            \
      bfr[n] = *(const short8v*)&Bsh[RB][c * 32 + sl * 8];                    \
    }                                                                         \
    _Pragma("unroll")                                                         \
    for (int m = 0; m < 8; ++m) {                                             \
      const int r  = wr * 128 + m * 16 + (lane & 15);                         \
      const int sl = (lane >> 4) ^ ((r >> 1) & 3);                            \
      afr[m] = *(const short8v*)&Ash[RB][r * 32 + sl * 8];                    \
    }                                                                         \
    if ((ktv) + 2 < NKT) { STAGE_A_S((ktv) + 2, RS); STAGE_B_S((ktv) + 2, RS); } \
    _Pragma("unroll")                                                         \
    for (int m = 0; m < 8; ++m)                                               \
      _Pragma("unroll")                                                       \
      for (int n = 0; n < 4; ++n)                                             \
        acc[m][n] = __builtin_amdgcn_mfma_f32_16x16x32_bf16(afr[m], bfr[n],   \
                                                            acc[m][n], 0, 0, 0); \
    /* ring safety: my ds_reads complete before peers overwrite the slot */   \
    asm volatile("s_waitcnt lgkmcnt(0)" ::: "memory");                        \
    if ((ktv) < NKT - 2) asm volatile("s_waitcnt vmcnt(4)" ::: "memory");     \
    else                 asm volatile("s_waitcnt vmcnt(0)" ::: "memory");     \
    __builtin_amdgcn_s_barrier();                                             \
    asm volatile("" ::: "memory");                                            \
    __builtin_amdgcn_sched_barrier(0);                                        \
  } while (0)

  #pragma unroll 1
  for (int u = 0; u < NKT / 3; ++u) {
    const int kt = u * 3;
    TILE_STEP(kt + 0, 0, 2);
    TILE_STEP(kt + 1, 1, 0);
    TILE_STEP(kt + 2, 2, 1);
  }
#undef TILE_STEP
#undef STAGE_A_S
#undef STAGE_B_S

  // ---- epilogue: per-row top-2 over this block's 256 codes (proven) ----
  __syncthreads();
  #pragma unroll
  for (int m = 0; m < 8; ++m) {
    #pragma unroll
    for (int reg = 0; reg < 4; ++reg) {
      float v1 = FLT_MAX, v2 = FLT_MAX; int i1 = 0, i2 = 0;
      #pragma unroll
      for (int n = 0; n < 4; ++n) {
        const float v = -2.0f * acc[m][n][reg];
        const int   c = col0 + wcn * 64 + n * 16 + (lane & 15);
        if (v < v1)      { v2 = v1; i2 = i1; v1 = v; i1 = c; }
        else if (v < v2) { v2 = v; i2 = c; }
      }
      #pragma unroll
      for (int off = 1; off < 16; off <<= 1) {
        const float ov1 = __shfl_xor(v1, off); const int oi1 = __shfl_xor(i1, off);
        const float ov2 = __shfl_xor(v2, off); const int oi2 = __shfl_xor(i2, off);
        if (ov1 < v1) {
          const float nv2 = (v1 < ov2) ? v1 : ov2;
          const int   ni2 = (v1 < ov2) ? i1 : oi2;
          v1 = ov1; i1 = oi1; v2 = nv2; i2 = ni2;
        } else if (ov1 < v2) { v2 = ov1; i2 = oi1; }
      }
      const int rloc = wr * 128 + m * 16 + (lane >> 4) * 4 + reg;
      if ((lane & 15) == 0)
        ltop[rloc][wcn] = make_float4(v1, __int_as_float(i1), v2, __int_as_float(i2));
    }
  }
  __syncthreads();
  if (t < BM) {
    float v1 = FLT_MAX, v2 = FLT_MAX; int i1 = 0x7fffffff, i2 = 0x7fffffff;
    #pragma unroll
    for (int g = 0; g < 4; ++g) {          // ascending wcn = ascending c
      const float4 P = ltop[t][g];
      const float pv1 = P.x; const int pi1 = __float_as_int(P.y);
      const float pv2 = P.z; const int pi2 = __float_as_int(P.w);
      if (pv1 < v1)      { v2 = v1; i2 = i1; v1 = pv1; i1 = pi1; }
      else if (pv1 < v2) { v2 = pv1; i2 = pi1; }
      if (pv2 < v1)      { v2 = v1; i2 = i1; v1 = pv2; i1 = pi2; }
      else if (pv2 < v2) { v2 = pv2; i2 = pi2; }
    }
    subtop[(size_t)(row0 + t) * NCB + blockIdx.x] =
        make_float4(v1, __int_as_float(i1), v2, __int_as_float(i2));
  }
}

// ---------------------------------------------------------------------------
// K3: selemit — fused select (r10-proven logic) + emit (r13-proven fusion).
// ---------------------------------------------------------------------------
__global__ __launch_bounds__(256)
void selemit_k(const float* __restrict__ z, const float* __restrict__ emb,
               const float* __restrict__ x2, const float4* __restrict__ subtop,
               float* __restrict__ out, double* __restrict__ partials) {
  __shared__ float zbuf[4][DIM];
  __shared__ float ebufA[4][DIM];
  __shared__ float ebufB[4][DIM];
  __shared__ double wsum[4];

  const int w    = threadIdx.x >> 6;
  const int lane = threadIdx.x & 63;
  const int n    = blockIdx.x * 4 + w;

  float v1 = FLT_MAX, v2 = FLT_MAX;
  int i1 = 0x7fffffff;
  if (lane < NCB) {
    const float4 e = subtop[(size_t)n * NCB + lane];
    v1 = e.x; i1 = __float_as_int(e.y);
    v2 = e.z;
  }

  float rowmin = v1;
  #pragma unroll
  for (int off = 32; off; off >>= 1) rowmin = fminf(rowmin, __shfl_xor(rowmin, off));
  const float thr = rowmin + MARGIN;

  const unsigned long long mA = __ballot(v1 <= thr);
  const unsigned long long mB = __ballot(v2 <= thr);

  int winner;
  if (mB == 0 && __popcll(mA) == 1) {
    winner = __shfl(i1, __builtin_ctzll(mA));
  } else {
    const float x2n = x2[n];
    {
      const float4* zg = (const float4*)(z + (size_t)n * DIM);
      float4* zl = (float4*)zbuf[w];
      #pragma unroll
      for (int i = 0; i < 3; ++i) zl[lane + 64 * i] = zg[lane + 64 * i];
    }
    float bd = FLT_MAX; int bc = 0x7fffffff;

    // ---- singles: block-winners not covered by a full-block sweep ----
    unsigned long long mS = mA & ~mB;
    while (mS) {
      const int s0 = __builtin_ctzll(mS); mS &= mS - 1;
      int s1 = -1;
      if (mS) { s1 = __builtin_ctzll(mS); mS &= mS - 1; }
      const int ca = __shfl(i1, s0);
      const int cb = (s1 >= 0) ? __shfl(i1, s1) : -1;
      {
        const float4* eg = (const float4*)(emb + (size_t)ca * DIM);
        float4* el = (float4*)ebufA[w];
        #pragma unroll
        for (int i = 0; i < 3; ++i) el[lane + 64 * i] = eg[lane + 64 * i];
      }
      if (cb >= 0) {
        const float4* eg = (const float4*)(emb + (size_t)cb * DIM);
        float4* el = (float4*)ebufB[w];
        #pragma unroll
        for (int i = 0; i < 3; ++i) el[lane + 64 * i] = eg[lane + 64 * i];
      }
      asm volatile("s_waitcnt lgkmcnt(0)" ::: "memory");
      const float4* zl4 = (const float4*)zbuf[w];
      const float4* la4 = (const float4*)ebufA[w];
      const float4* lb4 = (const float4*)ebufB[w];
      float da = 0.f, db = 0.f;
      #pragma unroll 8
      for (int kq = 0; kq < DIM / 4; ++kq) {   // exact k-sequential chains
        const float4 zz = zl4[kq];
        const float4 aa = la4[kq];
        const float4 bb = lb4[kq];
        da = fmaf(zz.x, aa.x, da); db = fmaf(zz.x, bb.x, db);
        da = fmaf(zz.y, aa.y, da); db = fmaf(zz.y, bb.y, db);
        da = fmaf(zz.z, aa.z, da); db = fmaf(zz.z, bb.z, db);
        da = fmaf(zz.w, aa.w, da); db = fmaf(zz.w, bb.w, db);
      }
      const float sa = x2n - 2.0f * da;
      if (sa < bd || (sa == bd && ca < bc)) { bd = sa; bc = ca; }
      if (cb >= 0) {
        const float sb = x2n - 2.0f * db;
        if (sb < bd || (sb == bd && cb < bc)) { bd = sb; bc = cb; }
      }
    }

    // ---- rare: full 256-code block sweeps (block v2 within margin) ----
    unsigned long long m = mB;
    if (m) {
      const float* zr = z + (size_t)n * DIM;
      float bdL = FLT_MAX; int bcL = 0x7fffffff;
      while (m) {
        const int s = __builtin_ctzll(m); m &= m - 1;
        const int c0 = s * BN + lane;
        const float* p0 = emb + (size_t)c0 * DIM;
        const float* p1 = p0 + (size_t)64 * DIM;
        const float* p2 = p0 + (size_t)128 * DIM;
        const float* p3 = p0 + (size_t)192 * DIM;
        float d0 = 0.f, d1 = 0.f, d2 = 0.f, d3 = 0.f;
        #pragma unroll 4
        for (int k = 0; k < DIM; ++k) {
          const float zk = zr[k];
          d0 = fmaf(zk, p0[k], d0);
          d1 = fmaf(zk, p1[k], d1);
          d2 = fmaf(zk, p2[k], d2);
          d3 = fmaf(zk, p3[k], d3);
        }
        const float s0 = x2n - 2.0f * d0;
        const float s1 = x2n - 2.0f * d1;
        const float s2 = x2n - 2.0f * d2;
        const float s3 = x2n - 2.0f * d3;
        if (s0 < bdL || (s0 == bdL && c0 < bcL))       { bdL = s0; bcL = c0; }
        if (s1 < bdL || (s1 == bdL && c0 + 64 < bcL))  { bdL = s1; bcL = c0 + 64; }
        if (s2 < bdL || (s2 == bdL && c0 + 128 < bcL)) { bdL = s2; bcL = c0 + 128; }
        if (s3 < bdL || (s3 == bdL && c0 + 192 < bcL)) { bdL = s3; bcL = c0 + 192; }
      }
      #pragma unroll
      for (int off = 32; off; off >>= 1) {
        const float ov = __shfl_xor(bdL, off);
        const int   oc = __shfl_xor(bcL, off);
        if (ov < bdL || (ov == bdL && oc < bcL)) { bdL = ov; bcL = oc; }
      }
      if (bdL < bd || (bdL == bd && bcL < bc)) { bd = bdL; bc = bcL; }
    }
    winner = bc;
  }

  // ---- emit (r10-proven numerics; same per-block loss grouping) ----
  const float4* zr4 = (const float4*)(z + (size_t)n * DIM);
  const float4* er4 = (const float4*)(emb + (size_t)winner * DIM);
  float4* outr = (float4*)(out + (size_t)n * DIM);
  double lsum = 0.0;
  #pragma unroll
  for (int i = 0; i < 3; ++i) {
    const int idx = lane + 64 * i;
    const float4 zz = zr4[idx];
    const float4 qq = er4[idx];
    float4 o;
    o.x = zz.x + (qq.x - zz.x); o.y = zz.y + (qq.y - zz.y);
    o.z = zz.z + (qq.z - zz.z); o.w = zz.w + (qq.w - zz.w);
    outr[idx] = o;
    const float dx = qq.x - zz.x, dy = qq.y - zz.y;
    const float dz = qq.z - zz.z, dw = qq.w - zz.w;
    lsum = fma((double)dx, (double)dx, lsum);
    lsum = fma((double)dy, (double)dy, lsum);
    lsum = fma((double)dz, (double)dz, lsum);
    lsum = fma((double)dw, (double)dw, lsum);
  }
  #pragma unroll
  for (int off = 32; off; off >>= 1) lsum += __shfl_xor(lsum, off);
  if (lane == 0) {
    out[(size_t)NROWS * DIM + n] = (float)winner;
    wsum[w] = lsum;
  }
  __syncthreads();
  if (threadIdx.x == 0)
    partials[blockIdx.x] = ((wsum[0] + wsum[1]) + (wsum[2] + wsum[3]));
}

// ---------------------------------------------------------------------------
// K4: deterministic 2-level loss reduce
// ---------------------------------------------------------------------------
__global__ __launch_bounds__(256)
void fin_kernel(const double* __restrict__ partials, float* __restrict__ out) {
  __shared__ double red[256];
  const int t = threadIdx.x;
  double s = 0.0;
  #pragma unroll
  for (int i = 0; i < NBLK_EMIT / 256; ++i) s += partials[t * (NBLK_EMIT / 256) + i];
  red[t] = s;
  __syncthreads();
  for (int off = 128; off; off >>= 1) {
    if (t < off) red[t] += red[t + off];
    __syncthreads();
  }
  if (t == 0)
    out[(size_t)NROWS * DIM + NROWS] =
        (float)(0.25 * red[0] / (double)((size_t)NROWS * DIM));
}

extern "C" void kernel_launch(void* const* d_in, const int* in_sizes, int n_in,
                              void* d_out, int out_size, void* d_ws, size_t ws_size,
                              hipStream_t stream) {
  const float* z   = (const float*)d_in[0];
  const float* emb = (const float*)d_in[1];
  float* out = (float*)d_out;
  char*  ws  = (char*)d_ws;

  // ws: partials 32KB | x2 64KB | (unused 64KB) | zh 24MB | eh 12MB | subtop 8MB
  double*   partials = (double*)ws;
  float*    x2       = (float*)(ws + 32768);
  ushort_t* zh       = (ushort_t*)(ws + 163840);
  ushort_t* eh       = (ushort_t*)(ws + 25329664);
  float4*   subtop   = (float4*)(ws + 37912576);

  cvt_all_kernel<<<NBLK_ZCVT + NBLK_ECVT, 256, 0, stream>>>(z, zh, x2, emb, eh);
  gemm5<<<dim3(KC / BN, NROWS / BM), 512, 0, stream>>>(zh, eh, subtop);
  selemit_k<<<NROWS / 4, 256, 0, stream>>>(z, emb, x2, subtop, out, partials);
  fin_kernel<<<1, 256, 0, stream>>>(partials, out);
}

// Round 17
// 450.725 us; speedup vs baseline: 1.0257x; 1.0257x over previous
//
#include <hip/hip_runtime.h>
#include <cfloat>

// Problem dims (fixed): z_e [8,2048,768] f32, embedding [8192,768] f32.
#define NROWS 16384
#define DIM   768
#define KC    8192
#define MARGIN 2.5e-4f
#define NBLK_EMIT (NROWS / 4)   // 4096 blocks, 4 rows each

// gemm6 tiling: 256x128 tile (72KB LDS -> 2 blocks/CU), 3-ring counted vmcnt
#define BM 256
#define BN 128
#define BK 32
#define NKT (DIM / BK)          // 24 K-tiles
#define NCB (KC / BN)           // 64 code-blocks per row

#define NBLK_ZCVT (NROWS / 4)           // 4096 blocks: z cvt + x2
#define NBLK_ECVT (KC * DIM / 8 / 256)  // 3072 blocks: emb cvt

typedef unsigned short ushort_t;
typedef __attribute__((ext_vector_type(8))) short short8v;  // 8 bf16 (4 VGPR)
typedef __attribute__((ext_vector_type(4))) float f32x4;

__device__ __forceinline__ ushort_t f2bf(float f) {
  unsigned u = __float_as_uint(f);
  return (ushort_t)((u + 0x7FFFu + ((u >> 16) & 1u)) >> 16);
}

__device__ __forceinline__ void gload_lds16(const void* g, void* l) {
  using GP = const __attribute__((address_space(1))) void*;
  using LP = __attribute__((address_space(3))) void*;
  GP gp = (GP)(unsigned long long)(uintptr_t)g;
  LP lp = (LP)(unsigned)(uintptr_t)l;
  __builtin_amdgcn_global_load_lds(gp, lp, 16, 0, 0);
}

// ---------------------------------------------------------------------------
// K0: merged conversion kernel (one launch) — r15/r16-proven.
// ---------------------------------------------------------------------------
__global__ __launch_bounds__(256)
void cvt_all_kernel(const float* __restrict__ z, ushort_t* __restrict__ zh,
                    float* __restrict__ x2, const float* __restrict__ emb,
                    ushort_t* __restrict__ eh) {
#pragma clang fp contract(off)
  if (blockIdx.x < NBLK_ZCVT) {
    const int w    = threadIdx.x >> 6;
    const int lane = threadIdx.x & 63;
    const int n    = blockIdx.x * 4 + w;
    const float* zr = z + (size_t)n * DIM;

    {
      const float4* zg = (const float4*)zr;
      uint2* zo = (uint2*)(zh + (size_t)n * DIM);
      #pragma unroll
      for (int i = 0; i < 3; ++i) {
        const float4 f = zg[lane + 64 * i];
        uint2 o;
        o.x = (unsigned)f2bf(f.x) | ((unsigned)f2bf(f.y) << 16);
        o.y = (unsigned)f2bf(f.z) | ((unsigned)f2bf(f.w) << 16);
        zo[lane + 64 * i] = o;
      }
    }

    const int chunk = lane >> 3;
    const int j     = lane & 7;
    const float* p  = zr + chunk * 96 + j;
    float v0 = p[0];
    float r  = v0 * v0;
    #pragma unroll
    for (int k = 1; k < 12; ++k) {
      const float v  = p[8 * k];
      const float sq = v * v;
      r = r + sq;
    }
    r = r + __shfl_xor(r, 1);
    r = r + __shfl_xor(r, 2);
    r = r + __shfl_xor(r, 4);
    r = r + __shfl_xor(r, 8);
    r = r + __shfl_xor(r, 16);
    r = r + __shfl_xor(r, 32);
    if (lane == 0) x2[n] = r;
  } else {
    const int i = (blockIdx.x - NBLK_ZCVT) * 256 + threadIdx.x;
    const float4* s4 = (const float4*)emb;
    const float4 f0 = s4[2 * i], f1 = s4[2 * i + 1];
    uint4 o;
    o.x = (unsigned)f2bf(f0.x) | ((unsigned)f2bf(f0.y) << 16);
    o.y = (unsigned)f2bf(f0.z) | ((unsigned)f2bf(f0.w) << 16);
    o.z = (unsigned)f2bf(f1.x) | ((unsigned)f2bf(f1.y) << 16);
    o.w = (unsigned)f2bf(f1.z) | ((unsigned)f2bf(f1.w) << 16);
    ((uint4*)eh)[i] = o;
  }
}

// ---------------------------------------------------------------------------
// K2: gemm6 — r16 K-loop structure (no intra-step drains, counted vmcnt,
// (r>>1)&3 swizzle both sides) at BM=256 x BN=128: LDS 72KB -> 2 blocks/CU
// co-residency (the untested matrix cell; r14's failure used a 2-ring with
// per-step vmcnt(0) drains — different lever).
// 8 waves in 4x2 grid, wave-tile 64x64, acc[4][4] (64 VGPR).
// Staging (gemm3/r12-proven slot-linear): thread t covers 16B slot t (row
// t>>2, slot t&3, source k-chunk pre-swizzled j=(t&3)^((r>>1)&3)); A = 2
// issues (rows 0-127, 128-255; +128 preserves (r>>1)&3 since 128>>1=64==0
// mod 4), B = 1 issue. 3 loads/thread/tile -> vmcnt(3) keeps the next
// tile's 3 loads in flight across the barrier (same invariant as the
// proven vmcnt(4)).
// Epilogue: per-row top-2 over 128 codes; ltop overlays Ash (r11/r12-proven).
// ---------------------------------------------------------------------------
__global__ __launch_bounds__(512)
void gemm6(const ushort_t* __restrict__ zh, const ushort_t* __restrict__ eh,
           float4* __restrict__ subtop) {
  __shared__ __align__(16) ushort_t Ash[3][BM * BK];   // 3 x 16KB
  __shared__ __align__(16) ushort_t Bsh[3][BN * BK];   // 3 x 8KB  (72KB total)

  const int t    = threadIdx.x;
  const int w    = t >> 6, lane = t & 63;
  const int wr   = w >> 1;          // 0..3 : 64-row quarter
  const int wcn  = w & 1;           // 0..1 : 64-col half
  const int row0 = blockIdx.y * BM;
  const int col0 = blockIdx.x * BN;
  const int l15  = lane & 15;
  // frag slot: k-chunk (lane>>4) at row rr (rr%16==l15, bits1-2 from l15)
  const int qa8  = ((lane >> 4) ^ ((lane >> 1) & 3)) * 8;

  // staging: thread t covers 16B slot t; row rS=t>>2, dest slot t&3,
  // source k-chunk j = (t&3) ^ ((rS>>1)&3)  [r12-proven]
  const int rS = t >> 2;
  const int jS = ((t & 3) ^ ((rS >> 1) & 3)) * 8;
  const ushort_t* srcA0 = zh + (size_t)(row0 + rS) * DIM + jS;
  const ushort_t* srcA1 = srcA0 + (size_t)128 * DIM;
  const ushort_t* srcB0 = eh + (size_t)(col0 + rS) * DIM + jS;

#define STG(ktv, SLOT) do {                                               \
    gload_lds16(srcA0 + (ktv) * 32, &Ash[SLOT][w * 512]);                 \
    gload_lds16(srcA1 + (ktv) * 32, &Ash[SLOT][4096 + w * 512]);          \
    gload_lds16(srcB0 + (ktv) * 32, &Bsh[SLOT][w * 512]);                 \
  } while (0)

  f32x4 acc[4][4];
  #pragma unroll
  for (int m = 0; m < 4; ++m)
    #pragma unroll
    for (int n = 0; n < 4; ++n) acc[m][n] = (f32x4){0.f, 0.f, 0.f, 0.f};

  // prologue: stage tiles 0,1 (3 loads each); wait tile 0 -> vmcnt(3)
  STG(0, 0);
  STG(1, 1);
  asm volatile("s_waitcnt vmcnt(3)" ::: "memory");
  __builtin_amdgcn_s_barrier();
  __builtin_amdgcn_sched_barrier(0);

#define TILE_STEP(ktv, RB, RS) do {                                           \
    short8v bfr[4], afr[4];                                                   \
    _Pragma("unroll")                                                         \
    for (int n = 0; n < 4; ++n) {                                             \
      const int c = wcn * 64 + n * 16 + l15;                                  \
      bfr[n] = *(const short8v*)&Bsh[RB][c * 32 + qa8];                       \
    }                                                                         \
    _Pragma("unroll")                                                         \
    for (int m = 0; m < 4; ++m) {                                             \
      const int r = wr * 64 + m * 16 + l15;                                   \
      afr[m] = *(const short8v*)&Ash[RB][r * 32 + qa8];                       \
    }                                                                         \
    if ((ktv) + 2 < NKT) STG((ktv) + 2, RS);                                  \
    _Pragma("unroll")                                                         \
    for (int m = 0; m < 4; ++m)                                               \
      _Pragma("unroll")                                                       \
      for (int n = 0; n < 4; ++n)                                             \
        acc[m][n] = __builtin_amdgcn_mfma_f32_16x16x32_bf16(afr[m], bfr[n],   \
                                                            acc[m][n], 0, 0, 0); \
    /* ring safety: my ds_reads complete before peers overwrite the slot */   \
    asm volatile("s_waitcnt lgkmcnt(0)" ::: "memory");                        \
    if ((ktv) < NKT - 2) asm volatile("s_waitcnt vmcnt(3)" ::: "memory");     \
    else                 asm volatile("s_waitcnt vmcnt(0)" ::: "memory");     \
    __builtin_amdgcn_s_barrier();                                             \
    asm volatile("" ::: "memory");                                            \
    __builtin_amdgcn_sched_barrier(0);                                        \
  } while (0)

  #pragma unroll 1
  for (int u = 0; u < NKT / 3; ++u) {
    const int kt = u * 3;
    TILE_STEP(kt + 0, 0, 2);
    TILE_STEP(kt + 1, 1, 0);
    TILE_STEP(kt + 2, 2, 1);
  }
#undef TILE_STEP
#undef STG

  // ---- epilogue: per-row top-2 over this block's 128 codes ----
  __syncthreads();
  float4* ltop = (float4*)(void*)&Ash[0][0];   // [256][2], 8KB overlay

  #pragma unroll
  for (int m = 0; m < 4; ++m) {
    #pragma unroll
    for (int reg = 0; reg < 4; ++reg) {
      float v1 = FLT_MAX, v2 = FLT_MAX; int i1 = 0, i2 = 0;
      #pragma unroll
      for (int n = 0; n < 4; ++n) {
        const float v = -2.0f * acc[m][n][reg];
        const int   c = col0 + wcn * 64 + n * 16 + l15;
        if (v < v1)      { v2 = v1; i2 = i1; v1 = v; i1 = c; }
        else if (v < v2) { v2 = v; i2 = c; }
      }
      #pragma unroll
      for (int off = 1; off < 16; off <<= 1) {
        const float ov1 = __shfl_xor(v1, off); const int oi1 = __shfl_xor(i1, off);
        const float ov2 = __shfl_xor(v2, off); const int oi2 = __shfl_xor(i2, off);
        if (ov1 < v1) {
          const float nv2 = (v1 < ov2) ? v1 : ov2;
          const int   ni2 = (v1 < ov2) ? i1 : oi2;
          v1 = ov1; i1 = oi1; v2 = nv2; i2 = ni2;
        } else if (ov1 < v2) { v2 = ov1; i2 = oi1; }
      }
      const int rloc = wr * 64 + m * 16 + (lane >> 4) * 4 + reg;
      if (l15 == 0)
        ltop[rloc * 2 + wcn] = make_float4(v1, __int_as_float(i1),
                                           v2, __int_as_float(i2));
    }
  }
  __syncthreads();
  if (t < BM) {
    float v1 = FLT_MAX, v2 = FLT_MAX; int i1 = 0x7fffffff, i2 = 0x7fffffff;
    #pragma unroll
    for (int g = 0; g < 2; ++g) {          // ascending wcn = ascending c
      const float4 P = ltop[t * 2 + g];
      const float pv1 = P.x; const int pi1 = __float_as_int(P.y);
      const float pv2 = P.z; const int pi2 = __float_as_int(P.w);
      if (pv1 < v1)      { v2 = v1; i2 = i1; v1 = pv1; i1 = pi1; }
      else if (pv1 < v2) { v2 = pv1; i2 = pi1; }
      if (pv2 < v1)      { v2 = v1; i2 = i1; v1 = pv2; i1 = pi2; }
      else if (pv2 < v2) { v2 = pv2; i2 = pi2; }
    }
    subtop[(size_t)(row0 + t) * NCB + blockIdx.x] =
        make_float4(v1, __int_as_float(i1), v2, __int_as_float(i2));
  }
}

// ---------------------------------------------------------------------------
// K3: selemit — fused select + emit (r13/r16-proven logic), NCB=64:
// all 64 lanes hold a block top-2; full-block sweep = 128 codes (2 ILP
// chains/lane). Margin/tie semantics and exact-chain numerics unchanged.
// ---------------------------------------------------------------------------
__global__ __launch_bounds__(256)
void selemit_k(const float* __restrict__ z, const float* __restrict__ emb,
               const float* __restrict__ x2, const float4* __restrict__ subtop,
               float* __restrict__ out, double* __restrict__ partials) {
  __shared__ float zbuf[4][DIM];
  __shared__ float ebufA[4][DIM];
  __shared__ float ebufB[4][DIM];
  __shared__ double wsum[4];

  const int w    = threadIdx.x >> 6;
  const int lane = threadIdx.x & 63;
  const int n    = blockIdx.x * 4 + w;

  float v1 = FLT_MAX, v2 = FLT_MAX;
  int i1 = 0x7fffffff;
  {
    const float4 e = subtop[(size_t)n * NCB + lane];
    v1 = e.x; i1 = __float_as_int(e.y);
    v2 = e.z;
  }

  float rowmin = v1;
  #pragma unroll
  for (int off = 32; off; off >>= 1) rowmin = fminf(rowmin, __shfl_xor(rowmin, off));
  const float thr = rowmin + MARGIN;

  const unsigned long long mA = __ballot(v1 <= thr);
  const unsigned long long mB = __ballot(v2 <= thr);

  int winner;
  if (mB == 0 && __popcll(mA) == 1) {
    winner = __shfl(i1, __builtin_ctzll(mA));
  } else {
    const float x2n = x2[n];
    {
      const float4* zg = (const float4*)(z + (size_t)n * DIM);
      float4* zl = (float4*)zbuf[w];
      #pragma unroll
      for (int i = 0; i < 3; ++i) zl[lane + 64 * i] = zg[lane + 64 * i];
    }
    float bd = FLT_MAX; int bc = 0x7fffffff;

    // ---- singles: block-winners not covered by a full-block sweep ----
    unsigned long long mS = mA & ~mB;
    while (mS) {
      const int s0 = __builtin_ctzll(mS); mS &= mS - 1;
      int s1 = -1;
      if (mS) { s1 = __builtin_ctzll(mS); mS &= mS - 1; }
      const int ca = __shfl(i1, s0);
      const int cb = (s1 >= 0) ? __shfl(i1, s1) : -1;
      {
        const float4* eg = (const float4*)(emb + (size_t)ca * DIM);
        float4* el = (float4*)ebufA[w];
        #pragma unroll
        for (int i = 0; i < 3; ++i) el[lane + 64 * i] = eg[lane + 64 * i];
      }
      if (cb >= 0) {
        const float4* eg = (const float4*)(emb + (size_t)cb * DIM);
        float4* el = (float4*)ebufB[w];
        #pragma unroll
        for (int i = 0; i < 3; ++i) el[lane + 64 * i] = eg[lane + 64 * i];
      }
      asm volatile("s_waitcnt lgkmcnt(0)" ::: "memory");
      const float4* zl4 = (const float4*)zbuf[w];
      const float4* la4 = (const float4*)ebufA[w];
      const float4* lb4 = (const float4*)ebufB[w];
      float da = 0.f, db = 0.f;
      #pragma unroll 8
      for (int kq = 0; kq < DIM / 4; ++kq) {   // exact k-sequential chains
        const float4 zz = zl4[kq];
        const float4 aa = la4[kq];
        const float4 bb = lb4[kq];
        da = fmaf(zz.x, aa.x, da); db = fmaf(zz.x, bb.x, db);
        da = fmaf(zz.y, aa.y, da); db = fmaf(zz.y, bb.y, db);
        da = fmaf(zz.z, aa.z, da); db = fmaf(zz.z, bb.z, db);
        da = fmaf(zz.w, aa.w, da); db = fmaf(zz.w, bb.w, db);
      }
      const float sa = x2n - 2.0f * da;
      if (sa < bd || (sa == bd && ca < bc)) { bd = sa; bc = ca; }
      if (cb >= 0) {
        const float sb = x2n - 2.0f * db;
        if (sb < bd || (sb == bd && cb < bc)) { bd = sb; bc = cb; }
      }
    }

    // ---- rare: full 128-code block sweeps (block v2 within margin) ----
    unsigned long long m = mB;
    if (m) {
      const float* zr = z + (size_t)n * DIM;
      float bdL = FLT_MAX; int bcL = 0x7fffffff;
      while (m) {
        const int s = __builtin_ctzll(m); m &= m - 1;
        const int c0 = s * BN + lane;
        const float* p0 = emb + (size_t)c0 * DIM;
        const float* p1 = p0 + (size_t)64 * DIM;
        float d0 = 0.f, d1 = 0.f;
        #pragma unroll 8
        for (int k = 0; k < DIM; ++k) {
          const float zk = zr[k];
          d0 = fmaf(zk, p0[k], d0);
          d1 = fmaf(zk, p1[k], d1);
        }
        const float s0 = x2n - 2.0f * d0;
        const float s1 = x2n - 2.0f * d1;
        if (s0 < bdL || (s0 == bdL && c0 < bcL))      { bdL = s0; bcL = c0; }
        if (s1 < bdL || (s1 == bdL && c0 + 64 < bcL)) { bdL = s1; bcL = c0 + 64; }
      }
      #pragma unroll
      for (int off = 32; off; off >>= 1) {
        const float ov = __shfl_xor(bdL, off);
        const int   oc = __shfl_xor(bcL, off);
        if (ov < bdL || (ov == bdL && oc < bcL)) { bdL = ov; bcL = oc; }
      }
      if (bdL < bd || (bdL == bd && bcL < bc)) { bd = bdL; bc = bcL; }
    }
    winner = bc;
  }

  // ---- emit (proven numerics; same per-block loss grouping) ----
  const float4* zr4 = (const float4*)(z + (size_t)n * DIM);
  const float4* er4 = (const float4*)(emb + (size_t)winner * DIM);
  float4* outr = (float4*)(out + (size_t)n * DIM);
  double lsum = 0.0;
  #pragma unroll
  for (int i = 0; i < 3; ++i) {
    const int idx = lane + 64 * i;
    const float4 zz = zr4[idx];
    const float4 qq = er4[idx];
    float4 o;
    o.x = zz.x + (qq.x - zz.x); o.y = zz.y + (qq.y - zz.y);
    o.z = zz.z + (qq.z - zz.z); o.w = zz.w + (qq.w - zz.w);
    outr[idx] = o;
    const float dx = qq.x - zz.x, dy = qq.y - zz.y;
    const float dz = qq.z - zz.z, dw = qq.w - zz.w;
    lsum = fma((double)dx, (double)dx, lsum);
    lsum = fma((double)dy, (double)dy, lsum);
    lsum = fma((double)dz, (double)dz, lsum);
    lsum = fma((double)dw, (double)dw, lsum);
  }
  #pragma unroll
  for (int off = 32; off; off >>= 1) lsum += __shfl_xor(lsum, off);
  if (lane == 0) {
    out[(size_t)NROWS * DIM + n] = (float)winner;
    wsum[w] = lsum;
  }
  __syncthreads();
  if (threadIdx.x == 0)
    partials[blockIdx.x] = ((wsum[0] + wsum[1]) + (wsum[2] + wsum[3]));
}

// ---------------------------------------------------------------------------
// K4: deterministic 2-level loss reduce
// ---------------------------------------------------------------------------
__global__ __launch_bounds__(256)
void fin_kernel(const double* __restrict__ partials, float* __restrict__ out) {
  __shared__ double red[256];
  const int t = threadIdx.x;
  double s = 0.0;
  #pragma unroll
  for (int i = 0; i < NBLK_EMIT / 256; ++i) s += partials[t * (NBLK_EMIT / 256) + i];
  red[t] = s;
  __syncthreads();
  for (int off = 128; off; off >>= 1) {
    if (t < off) red[t] += red[t + off];
    __syncthreads();
  }
  if (t == 0)
    out[(size_t)NROWS * DIM + NROWS] =
        (float)(0.25 * red[0] / (double)((size_t)NROWS * DIM));
}

extern "C" void kernel_launch(void* const* d_in, const int* in_sizes, int n_in,
                              void* d_out, int out_size, void* d_ws, size_t ws_size,
                              hipStream_t stream) {
  const float* z   = (const float*)d_in[0];
  const float* emb = (const float*)d_in[1];
  float* out = (float*)d_out;
  char*  ws  = (char*)d_ws;

  // ws: partials 32KB | x2 64KB | (unused 64KB) | zh 24MB | eh 12MB | subtop 16MB
  double*   partials = (double*)ws;
  float*    x2       = (float*)(ws + 32768);
  ushort_t* zh       = (ushort_t*)(ws + 163840);
  ushort_t* eh       = (ushort_t*)(ws + 25329664);
  float4*   subtop   = (float4*)(ws + 37912576);

  cvt_all_kernel<<<NBLK_ZCVT + NBLK_ECVT, 256, 0, stream>>>(z, zh, x2, emb, eh);
  gemm6<<<dim3(KC / BN, NROWS / BM), 512, 0, stream>>>(zh, eh, subtop);
  selemit_k<<<NROWS / 4, 256, 0, stream>>>(z, emb, x2, subtop, out, partials);
  fin_kernel<<<1, 256, 0, stream>>>(partials, out);
}

// Round 18
// 418.152 us; speedup vs baseline: 1.1056x; 1.0779x over previous
//
#include <hip/hip_runtime.h>
#include <cfloat>

// Problem dims (fixed): z_e [8,2048,768] f32, embedding [8192,768] f32.
#define NROWS 16384
#define DIM   768
#define KC    8192
#define MARGIN 2.5e-4f
#define NBLK_EMIT (NROWS / 4)   // 4096 blocks, 4 rows each

// gemm tiling (r16-proven): 256x256 tile, 3-ring counted vmcnt
#define BM 256
#define BN 256
#define BK 32
#define NKT (DIM / BK)          // 24 K-tiles
#define SELBN 128               // selemit block granularity (r17-proven win)
#define NCB (KC / SELBN)        // 64 code-blocks per row in subtop

#define NBLK_ZCVT (NROWS / 4)           // 4096 blocks: z cvt + x2
#define NBLK_ECVT (KC * DIM / 8 / 256)  // 3072 blocks: emb cvt

typedef unsigned short ushort_t;
typedef __attribute__((ext_vector_type(8))) short short8v;  // 8 bf16 (4 VGPR)
typedef __attribute__((ext_vector_type(4))) float f32x4;

__device__ __forceinline__ ushort_t f2bf(float f) {
  unsigned u = __float_as_uint(f);
  return (ushort_t)((u + 0x7FFFu + ((u >> 16) & 1u)) >> 16);
}

__device__ __forceinline__ void gload_lds16(const void* g, void* l) {
  using GP = const __attribute__((address_space(1))) void*;
  using LP = __attribute__((address_space(3))) void*;
  GP gp = (GP)(unsigned long long)(uintptr_t)g;
  LP lp = (LP)(unsigned)(uintptr_t)l;
  __builtin_amdgcn_global_load_lds(gp, lp, 16, 0, 0);
}

// ---------------------------------------------------------------------------
// K0: merged conversion kernel (one launch) — r15/r16-proven.
// ---------------------------------------------------------------------------
__global__ __launch_bounds__(256)
void cvt_all_kernel(const float* __restrict__ z, ushort_t* __restrict__ zh,
                    float* __restrict__ x2, const float* __restrict__ emb,
                    ushort_t* __restrict__ eh) {
#pragma clang fp contract(off)
  if (blockIdx.x < NBLK_ZCVT) {
    const int w    = threadIdx.x >> 6;
    const int lane = threadIdx.x & 63;
    const int n    = blockIdx.x * 4 + w;
    const float* zr = z + (size_t)n * DIM;

    {
      const float4* zg = (const float4*)zr;
      uint2* zo = (uint2*)(zh + (size_t)n * DIM);
      #pragma unroll
      for (int i = 0; i < 3; ++i) {
        const float4 f = zg[lane + 64 * i];
        uint2 o;
        o.x = (unsigned)f2bf(f.x) | ((unsigned)f2bf(f.y) << 16);
        o.y = (unsigned)f2bf(f.z) | ((unsigned)f2bf(f.w) << 16);
        zo[lane + 64 * i] = o;
      }
    }

    const int chunk = lane >> 3;
    const int j     = lane & 7;
    const float* p  = zr + chunk * 96 + j;
    float v0 = p[0];
    float r  = v0 * v0;
    #pragma unroll
    for (int k = 1; k < 12; ++k) {
      const float v  = p[8 * k];
      const float sq = v * v;
      r = r + sq;
    }
    r = r + __shfl_xor(r, 1);
    r = r + __shfl_xor(r, 2);
    r = r + __shfl_xor(r, 4);
    r = r + __shfl_xor(r, 8);
    r = r + __shfl_xor(r, 16);
    r = r + __shfl_xor(r, 32);
    if (lane == 0) x2[n] = r;
  } else {
    const int i = (blockIdx.x - NBLK_ZCVT) * 256 + threadIdx.x;
    const float4* s4 = (const float4*)emb;
    const float4 f0 = s4[2 * i], f1 = s4[2 * i + 1];
    uint4 o;
    o.x = (unsigned)f2bf(f0.x) | ((unsigned)f2bf(f0.y) << 16);
    o.y = (unsigned)f2bf(f0.z) | ((unsigned)f2bf(f0.w) << 16);
    o.z = (unsigned)f2bf(f1.x) | ((unsigned)f2bf(f1.y) << 16);
    o.w = (unsigned)f2bf(f1.z) | ((unsigned)f2bf(f1.w) << 16);
    ((uint4*)eh)[i] = o;
  }
}

// ---------------------------------------------------------------------------
// K2: gemm5b — EXACT r16-proven K-loop (325 us: no intra-step drains,
// counted vmcnt(4), (r>>1)&3 swizzle, 3-ring, natural block order,
// __launch_bounds__(512,2)). ONLY the final t<BM merge changed: emit TWO
// 128-code top-2s per block (wcn pairs {0,1},{2,3}) -> NCB=64 subtop,
// which r17 proved cuts selemit time ~50us (finer blocks => top-2 codes
// land in different blocks => cheap singles path instead of full sweeps).
// acc liveness unchanged (merge runs after acc is dead) — no spill risk.
// ---------------------------------------------------------------------------
__global__ __launch_bounds__(512, 2)
void gemm5b(const ushort_t* __restrict__ zh, const ushort_t* __restrict__ eh,
            float4* __restrict__ subtop) {
  __shared__ __align__(16) ushort_t Ash[3][BM * BK];   // 3 x 16KB
  __shared__ __align__(16) ushort_t Bsh[3][BN * BK];   // 3 x 16KB
  __shared__ float4 ltop[BM][4];                       // 16KB

  const int t    = threadIdx.x;
  const int w    = t >> 6, lane = t & 63;
  const int wr   = w >> 2;          // 0..1 : 128-row half
  const int wcn  = w & 3;           // 0..3 : 64-col group
  const int row0 = blockIdx.y * BM;
  const int col0 = blockIdx.x * BN;

  const int srow  = w * 32 + (lane >> 2);
  const int sslot = lane & 3;
  const ushort_t* zsA[2];
  const ushort_t* esB[2];
  #pragma unroll
  for (int q = 0; q < 2; ++q) {
    const int r = srow + q * 16;
    const int j = sslot ^ ((r >> 1) & 3);
    zsA[q] = zh + (size_t)(row0 + r) * DIM + j * 8;
    esB[q] = eh + (size_t)(col0 + r) * DIM + j * 8;
  }

#define STAGE_A_S(ktv, SLOT) do {                                         \
    _Pragma("unroll")                                                     \
    for (int q = 0; q < 2; ++q)                                           \
      gload_lds16(zsA[q] + (ktv) * 32, &Ash[SLOT][w * 1024 + q * 512]);   \
  } while (0)
#define STAGE_B_S(ktv, SLOT) do {                                         \
    _Pragma("unroll")                                                     \
    for (int q = 0; q < 2; ++q)                                           \
      gload_lds16(esB[q] + (ktv) * 32, &Bsh[SLOT][w * 1024 + q * 512]);   \
  } while (0)

  f32x4 acc[8][4];
  #pragma unroll
  for (int m = 0; m < 8; ++m)
    #pragma unroll
    for (int n = 0; n < 4; ++n) acc[m][n] = (f32x4){0.f, 0.f, 0.f, 0.f};

  STAGE_A_S(0, 0); STAGE_B_S(0, 0);
  STAGE_A_S(1, 1); STAGE_B_S(1, 1);
  asm volatile("s_waitcnt vmcnt(4)" ::: "memory");
  __builtin_amdgcn_s_barrier();
  __builtin_amdgcn_sched_barrier(0);

#define TILE_STEP(ktv, RB, RS) do {                                           \
    short8v bfr[4], afr[8];                                                   \
    _Pragma("unroll")                                                         \
    for (int n = 0; n < 4; ++n) {                                             \
      const int c  = wcn * 64 + n * 16 + (lane & 15);                         \
      const int sl = (lane >> 4) ^ ((c >> 1) & 3);                            \
      bfr[n] = *(const short8v*)&Bsh[RB][c * 32 + sl * 8];                    \
    }                                                                         \
    _Pragma("unroll")                                                         \
    for (int m = 0; m < 8; ++m) {                                             \
      const int r  = wr * 128 + m * 16 + (lane & 15);                         \
      const int sl = (lane >> 4) ^ ((r >> 1) & 3);                            \
      afr[m] = *(const short8v*)&Ash[RB][r * 32 + sl * 8];                    \
    }                                                                         \
    if ((ktv) + 2 < NKT) { STAGE_A_S((ktv) + 2, RS); STAGE_B_S((ktv) + 2, RS); } \
    _Pragma("unroll")                                                         \
    for (int m = 0; m < 8; ++m)                                               \
      _Pragma("unroll")                                                       \
      for (int n = 0; n < 4; ++n)                                             \
        acc[m][n] = __builtin_amdgcn_mfma_f32_16x16x32_bf16(afr[m], bfr[n],   \
                                                            acc[m][n], 0, 0, 0); \
    asm volatile("s_waitcnt lgkmcnt(0)" ::: "memory");                        \
    if ((ktv) < NKT - 2) asm volatile("s_waitcnt vmcnt(4)" ::: "memory");     \
    else                 asm volatile("s_waitcnt vmcnt(0)" ::: "memory");     \
    __builtin_amdgcn_s_barrier();                                             \
    asm volatile("" ::: "memory");                                            \
    __builtin_amdgcn_sched_barrier(0);                                        \
  } while (0)

  #pragma unroll 1
  for (int u = 0; u < NKT / 3; ++u) {
    const int kt = u * 3;
    TILE_STEP(kt + 0, 0, 2);
    TILE_STEP(kt + 1, 1, 0);
    TILE_STEP(kt + 2, 2, 1);
  }
#undef TILE_STEP
#undef STAGE_A_S
#undef STAGE_B_S

  // ---- epilogue: per-row per-64-col-group top-2 (shuffle merge: proven) ----
  __syncthreads();
  #pragma unroll
  for (int m = 0; m < 8; ++m) {
    #pragma unroll
    for (int reg = 0; reg < 4; ++reg) {
      float v1 = FLT_MAX, v2 = FLT_MAX; int i1 = 0, i2 = 0;
      #pragma unroll
      for (int n = 0; n < 4; ++n) {
        const float v = -2.0f * acc[m][n][reg];
        const int   c = col0 + wcn * 64 + n * 16 + (lane & 15);
        if (v < v1)      { v2 = v1; i2 = i1; v1 = v; i1 = c; }
        else if (v < v2) { v2 = v; i2 = c; }
      }
      #pragma unroll
      for (int off = 1; off < 16; off <<= 1) {
        const float ov1 = __shfl_xor(v1, off); const int oi1 = __shfl_xor(i1, off);
        const float ov2 = __shfl_xor(v2, off); const int oi2 = __shfl_xor(i2, off);
        if (ov1 < v1) {
          const float nv2 = (v1 < ov2) ? v1 : ov2;
          const int   ni2 = (v1 < ov2) ? i1 : oi2;
          v1 = ov1; i1 = oi1; v2 = nv2; i2 = ni2;
        } else if (ov1 < v2) { v2 = ov1; i2 = oi1; }
      }
      const int rloc = wr * 128 + m * 16 + (lane >> 4) * 4 + reg;
      if ((lane & 15) == 0)
        ltop[rloc][wcn] = make_float4(v1, __int_as_float(i1), v2, __int_as_float(i2));
    }
  }
  __syncthreads();
  // final merge: TWO 128-code top-2s per row (wcn pairs {0,1} and {2,3})
  if (t < BM) {
    #pragma unroll
    for (int h = 0; h < 2; ++h) {
      float v1 = FLT_MAX, v2 = FLT_MAX; int i1 = 0x7fffffff, i2 = 0x7fffffff;
      #pragma unroll
      for (int g = 2 * h; g < 2 * h + 2; ++g) {   // ascending wcn = ascending c
        const float4 P = ltop[t][g];
        const float pv1 = P.x; const int pi1 = __float_as_int(P.y);
        const float pv2 = P.z; const int pi2 = __float_as_int(P.w);
        if (pv1 < v1)      { v2 = v1; i2 = i1; v1 = pv1; i1 = pi1; }
        else if (pv1 < v2) { v2 = pv1; i2 = pi1; }
        if (pv2 < v1)      { v2 = v1; i2 = i1; v1 = pv2; i1 = pi2; }
        else if (pv2 < v2) { v2 = pv2; i2 = pi2; }
      }
      subtop[(size_t)(row0 + t) * NCB + blockIdx.x * 2 + h] =
          make_float4(v1, __int_as_float(i1), v2, __int_as_float(i2));
    }
  }
}

// ---------------------------------------------------------------------------
// K3: selemit — r17-proven NCB=64 version: all 64 lanes hold a 128-code
// block top-2; full-block sweep = 128 codes (2 ILP chains/lane).
// ---------------------------------------------------------------------------
__global__ __launch_bounds__(256)
void selemit_k(const float* __restrict__ z, const float* __restrict__ emb,
               const float* __restrict__ x2, const float4* __restrict__ subtop,
               float* __restrict__ out, double* __restrict__ partials) {
  __shared__ float zbuf[4][DIM];
  __shared__ float ebufA[4][DIM];
  __shared__ float ebufB[4][DIM];
  __shared__ double wsum[4];

  const int w    = threadIdx.x >> 6;
  const int lane = threadIdx.x & 63;
  const int n    = blockIdx.x * 4 + w;

  float v1 = FLT_MAX, v2 = FLT_MAX;
  int i1 = 0x7fffffff;
  {
    const float4 e = subtop[(size_t)n * NCB + lane];
    v1 = e.x; i1 = __float_as_int(e.y);
    v2 = e.z;
  }

  float rowmin = v1;
  #pragma unroll
  for (int off = 32; off; off >>= 1) rowmin = fminf(rowmin, __shfl_xor(rowmin, off));
  const float thr = rowmin + MARGIN;

  const unsigned long long mA = __ballot(v1 <= thr);
  const unsigned long long mB = __ballot(v2 <= thr);

  int winner;
  if (mB == 0 && __popcll(mA) == 1) {
    winner = __shfl(i1, __builtin_ctzll(mA));
  } else {
    const float x2n = x2[n];
    {
      const float4* zg = (const float4*)(z + (size_t)n * DIM);
      float4* zl = (float4*)zbuf[w];
      #pragma unroll
      for (int i = 0; i < 3; ++i) zl[lane + 64 * i] = zg[lane + 64 * i];
    }
    float bd = FLT_MAX; int bc = 0x7fffffff;

    // ---- singles: block-winners not covered by a full-block sweep ----
    unsigned long long mS = mA & ~mB;
    while (mS) {
      const int s0 = __builtin_ctzll(mS); mS &= mS - 1;
      int s1 = -1;
      if (mS) { s1 = __builtin_ctzll(mS); mS &= mS - 1; }
      const int ca = __shfl(i1, s0);
      const int cb = (s1 >= 0) ? __shfl(i1, s1) : -1;
      {
        const float4* eg = (const float4*)(emb + (size_t)ca * DIM);
        float4* el = (float4*)ebufA[w];
        #pragma unroll
        for (int i = 0; i < 3; ++i) el[lane + 64 * i] = eg[lane + 64 * i];
      }
      if (cb >= 0) {
        const float4* eg = (const float4*)(emb + (size_t)cb * DIM);
        float4* el = (float4*)ebufB[w];
        #pragma unroll
        for (int i = 0; i < 3; ++i) el[lane + 64 * i] = eg[lane + 64 * i];
      }
      asm volatile("s_waitcnt lgkmcnt(0)" ::: "memory");
      const float4* zl4 = (const float4*)zbuf[w];
      const float4* la4 = (const float4*)ebufA[w];
      const float4* lb4 = (const float4*)ebufB[w];
      float da = 0.f, db = 0.f;
      #pragma unroll 8
      for (int kq = 0; kq < DIM / 4; ++kq) {   // exact k-sequential chains
        const float4 zz = zl4[kq];
        const float4 aa = la4[kq];
        const float4 bb = lb4[kq];
        da = fmaf(zz.x, aa.x, da); db = fmaf(zz.x, bb.x, db);
        da = fmaf(zz.y, aa.y, da); db = fmaf(zz.y, bb.y, db);
        da = fmaf(zz.z, aa.z, da); db = fmaf(zz.z, bb.z, db);
        da = fmaf(zz.w, aa.w, da); db = fmaf(zz.w, bb.w, db);
      }
      const float sa = x2n - 2.0f * da;
      if (sa < bd || (sa == bd && ca < bc)) { bd = sa; bc = ca; }
      if (cb >= 0) {
        const float sb = x2n - 2.0f * db;
        if (sb < bd || (sb == bd && cb < bc)) { bd = sb; bc = cb; }
      }
    }

    // ---- rare: full 128-code block sweeps (block v2 within margin) ----
    unsigned long long m = mB;
    if (m) {
      const float* zr = z + (size_t)n * DIM;
      float bdL = FLT_MAX; int bcL = 0x7fffffff;
      while (m) {
        const int s = __builtin_ctzll(m); m &= m - 1;
        const int c0 = s * SELBN + lane;
        const float* p0 = emb + (size_t)c0 * DIM;
        const float* p1 = p0 + (size_t)64 * DIM;
        float d0 = 0.f, d1 = 0.f;
        #pragma unroll 8
        for (int k = 0; k < DIM; ++k) {
          const float zk = zr[k];
          d0 = fmaf(zk, p0[k], d0);
          d1 = fmaf(zk, p1[k], d1);
        }
        const float s0 = x2n - 2.0f * d0;
        const float s1 = x2n - 2.0f * d1;
        if (s0 < bdL || (s0 == bdL && c0 < bcL))      { bdL = s0; bcL = c0; }
        if (s1 < bdL || (s1 == bdL && c0 + 64 < bcL)) { bdL = s1; bcL = c0 + 64; }
      }
      #pragma unroll
      for (int off = 32; off; off >>= 1) {
        const float ov = __shfl_xor(bdL, off);
        const int   oc = __shfl_xor(bcL, off);
        if (ov < bdL || (ov == bdL && oc < bcL)) { bdL = ov; bcL = oc; }
      }
      if (bdL < bd || (bdL == bd && bcL < bc)) { bd = bdL; bc = bcL; }
    }
    winner = bc;
  }

  // ---- emit (proven numerics; same per-block loss grouping) ----
  const float4* zr4 = (const float4*)(z + (size_t)n * DIM);
  const float4* er4 = (const float4*)(emb + (size_t)winner * DIM);
  float4* outr = (float4*)(out + (size_t)n * DIM);
  double lsum = 0.0;
  #pragma unroll
  for (int i = 0; i < 3; ++i) {
    const int idx = lane + 64 * i;
    const float4 zz = zr4[idx];
    const float4 qq = er4[idx];
    float4 o;
    o.x = zz.x + (qq.x - zz.x); o.y = zz.y + (qq.y - zz.y);
    o.z = zz.z + (qq.z - zz.z); o.w = zz.w + (qq.w - zz.w);
    outr[idx] = o;
    const float dx = qq.x - zz.x, dy = qq.y - zz.y;
    const float dz = qq.z - zz.z, dw = qq.w - zz.w;
    lsum = fma((double)dx, (double)dx, lsum);
    lsum = fma((double)dy, (double)dy, lsum);
    lsum = fma((double)dz, (double)dz, lsum);
    lsum = fma((double)dw, (double)dw, lsum);
  }
  #pragma unroll
  for (int off = 32; off; off >>= 1) lsum += __shfl_xor(lsum, off);
  if (lane == 0) {
    out[(size_t)NROWS * DIM + n] = (float)winner;
    wsum[w] = lsum;
  }
  __syncthreads();
  if (threadIdx.x == 0)
    partials[blockIdx.x] = ((wsum[0] + wsum[1]) + (wsum[2] + wsum[3]));
}

// ---------------------------------------------------------------------------
// K4: deterministic 2-level loss reduce
// ---------------------------------------------------------------------------
__global__ __launch_bounds__(256)
void fin_kernel(const double* __restrict__ partials, float* __restrict__ out) {
  __shared__ double red[256];
  const int t = threadIdx.x;
  double s = 0.0;
  #pragma unroll
  for (int i = 0; i < NBLK_EMIT / 256; ++i) s += partials[t * (NBLK_EMIT / 256) + i];
  red[t] = s;
  __syncthreads();
  for (int off = 128; off; off >>= 1) {
    if (t < off) red[t] += red[t + off];
    __syncthreads();
  }
  if (t == 0)
    out[(size_t)NROWS * DIM + NROWS] =
        (float)(0.25 * red[0] / (double)((size_t)NROWS * DIM));
}

extern "C" void kernel_launch(void* const* d_in, const int* in_sizes, int n_in,
                              void* d_out, int out_size, void* d_ws, size_t ws_size,
                              hipStream_t stream) {
  const float* z   = (const float*)d_in[0];
  const float* emb = (const float*)d_in[1];
  float* out = (float*)d_out;
  char*  ws  = (char*)d_ws;

  // ws: partials 32KB | x2 64KB | (unused 64KB) | zh 24MB | eh 12MB | subtop 16MB
  double*   partials = (double*)ws;
  float*    x2       = (float*)(ws + 32768);
  ushort_t* zh       = (ushort_t*)(ws + 163840);
  ushort_t* eh       = (ushort_t*)(ws + 25329664);
  float4*   subtop   = (float4*)(ws + 37912576);

  cvt_all_kernel<<<NBLK_ZCVT + NBLK_ECVT, 256, 0, stream>>>(z, zh, x2, emb, eh);
  gemm5b<<<dim3(KC / BN, NROWS / BM), 512, 0, stream>>>(zh, eh, subtop);
  selemit_k<<<NROWS / 4, 256, 0, stream>>>(z, emb, x2, subtop, out, partials);
  fin_kernel<<<1, 256, 0, stream>>>(partials, out);
}